// Round 7
// baseline (354.843 us; speedup 1.0000x reference)
//
#include <hip/hip_runtime.h>
#include <cstdint>
#include <cstddef>

#define C_CH 128
#define T_TOK 9216
#define H_IMG 96
#define W_IMG 96
#define NSTATE 8

// fused scan tiling: 64 output tokens, 32-token warm-up halo each direction.
#define CHUNK 64
#define RHALO 32
#define REGION (CHUNK + 2 * RHALO)   // 128

__device__ __forceinline__ float siluf_dev(float x) {
  return x / (1.0f + expf(-x));
}

__device__ __forceinline__ float fast_silu(float x) {
  // x * sigmoid(x) with native rcp; binary-thresholded output tolerates ~2ulp
  return __fdividef(x, 1.0f + __expf(-x));
}

// ---------------------------------------------------------------------------
// K0: slot assignment from record_len (int32!) + v = out_proj_w @ mlp_w
// ---------------------------------------------------------------------------
__global__ __launch_bounds__(128) void k0_setup(
    const int* __restrict__ rec, int n_groups, int N,
    const float* __restrict__ out_proj_w, const float* __restrict__ mlp_w,
    float* __restrict__ vvec, int* __restrict__ slot)
{
  const int tid = threadIdx.x;
  if (tid == 0) {
    int f = 0, sl = 0;
    for (int g = 0; g < n_groups; ++g) {
      const int L = rec[g];
      slot[f] = -1;                       // ego / single frame -> mask = 1
      for (int i = 1; i < L; ++i) slot[f + i] = sl++;
      f += L;
    }
  }
  if (tid < C_CH) {
    float acc = 0.0f;
    for (int j = 0; j < C_CH; ++j) acc += out_proj_w[tid * C_CH + j] * mlp_w[j];
    vvec[tid] = acc;
  }
}

// ---------------------------------------------------------------------------
// K1: rmsnorm + xz = xn @ in_proj. R7: M-tile 64 -> 32 tokens.
// LDS 18.6 KB -> 8 blocks/CU (was 4 at 35.3 KB); launch_bounds(256,8)
// -> 32 waves/CU (2x latency hiding for the b4 global stream).
// Per thread: acc[2][4], 4096 FMAs. B streamed from global (L2-hot,
// 16-lane address groups coalesce to 256B). rms_w folded into Asm.
// ---------------------------------------------------------------------------
__global__ __launch_bounds__(256, 8) void k1_gemm(
    const float* __restrict__ feats, const float* __restrict__ in_proj,
    const float* __restrict__ rms_w, const float* __restrict__ mlp_w,
    const float* __restrict__ mlp_b, const float* __restrict__ vvec,
    const int* __restrict__ slot,
    float* __restrict__ xipre, float* __restrict__ wbuf,
    float* __restrict__ logit)
{
  __shared__ float Asm[C_CH * 32];   // A[k][t]  (raw x, then ir*rw-scaled) 16 KB
  __shared__ float redA[256], redB[256], irS[32];
  const int f = blockIdx.y;
  const int s = slot[f];
  if (s < 0) return;
  const int m0 = blockIdx.x * 32;
  const int tid = threadIdx.x;

  // stage A: x[c][t], coalesced along t (8 lanes x 4 floats = 128B/channel)
  {
    const int c0 = tid >> 3;           // 0..31
    const int tq = (tid & 7) * 4;      // 0..28
    const float* src = feats + (size_t)f * C_CH * T_TOK + m0 + tq;
    #pragma unroll
    for (int i = 0; i < 4; ++i) {
      const int c = c0 + i * 32;
      const float4 x4 = *(const float4*)(src + (size_t)c * T_TOK);
      *(float4*)&Asm[c * 32 + tq] = x4;
    }
  }
  __syncthreads();
  // pre-pass: per-token rms + logit init (res . mlp_w + b), 8 threads/token
  {
    const int t = tid & 31;
    const int q = tid >> 5;            // 0..7
    float ssum = 0.0f, rm = 0.0f;
    for (int cc = q * 16; cc < q * 16 + 16; ++cc) {
      const float val = Asm[cc * 32 + t];
      ssum += val * val;
      rm += val * mlp_w[cc];
    }
    redA[tid] = ssum; redB[tid] = rm;
  }
  __syncthreads();
  if (tid < 32) {
    const int t = tid;
    float ssum = 0.0f, rm = 0.0f;
    #pragma unroll
    for (int j = 0; j < 8; ++j) { ssum += redA[t + 32 * j]; rm += redB[t + 32 * j]; }
    const float ir = 1.0f / sqrtf(ssum * (1.0f / C_CH) + 1e-5f);
    logit[(size_t)s * T_TOK + m0 + t] = rm + mlp_b[0];
    irS[t] = ir;
  }
  __syncthreads();
  {
    const int t = tid & 31;
    const int q = tid >> 5;
    const float ir = irS[t];
    for (int cc = q * 16; cc < q * 16 + 16; ++cc)
      Asm[cc * 32 + t] = (Asm[cc * 32 + t] * ir) * rms_w[cc];
  }
  __syncthreads();

  const int ti = tid >> 4;   // 0..15 -> rows ti*2..+1
  const int tc = tid & 15;   // 0..15 -> cols tc*4..+3
  for (int chunk = 0; chunk < 4; ++chunk) {
    const int n0 = chunk * 64;
    const float* bp = in_proj + n0 + tc * 4;
    float acc[2][4];
    #pragma unroll
    for (int i = 0; i < 2; ++i)
      #pragma unroll
      for (int j = 0; j < 4; ++j) acc[i][j] = 0.0f;
    #pragma unroll 8
    for (int k = 0; k < C_CH; ++k) {
      const float2 a2 = *(const float2*)&Asm[k * 32 + ti * 2];
      const float4 b4 = *(const float4*)(bp + (size_t)k * 256);
      acc[0][0] += a2.x * b4.x; acc[0][1] += a2.x * b4.y; acc[0][2] += a2.x * b4.z; acc[0][3] += a2.x * b4.w;
      acc[1][0] += a2.y * b4.x; acc[1][1] += a2.y * b4.y; acc[1][2] += a2.y * b4.z; acc[1][3] += a2.y * b4.w;
    }
    if (chunk < 2) {
      const int cb = n0 + tc * 4;     // xi channel 0..127
      #pragma unroll
      for (int i = 0; i < 2; ++i) {
        const int t = m0 + ti * 2 + i;
        float4 o; o.x = acc[i][0]; o.y = acc[i][1]; o.z = acc[i][2]; o.w = acc[i][3];
        *(float4*)&xipre[((size_t)s * T_TOK + t) * C_CH + cb] = o;
      }
    } else {
      const int zc = (chunk - 2) * 64 + tc * 4;  // z channel 0..127
      const float4 v4 = *(const float4*)&vvec[zc];
      #pragma unroll
      for (int i = 0; i < 2; ++i) {
        const int t = m0 + ti * 2 + i;
        float4 o;
        o.x = 0.5f * siluf_dev(acc[i][0]) * v4.x;
        o.y = 0.5f * siluf_dev(acc[i][1]) * v4.y;
        o.z = 0.5f * siluf_dev(acc[i][2]) * v4.z;
        o.w = 0.5f * siluf_dev(acc[i][3]) * v4.w;
        *(float4*)&wbuf[((size_t)s * T_TOK + t) * C_CH + zc] = o;
      }
    }
  }
}

// ---------------------------------------------------------------------------
// K2: conv+silu -> xi_g[t][c]; projection -> B,C -> bc_g[t][16] and dt -> LDS;
// delta[t][c] = softplus(dt . dt_proj_w[:,c] + b[c]) -> delta_g[t][c].
// LDS: xibuf 33 KB + dtb 2 KB = 35 KB, 4 blocks/CU.
// ---------------------------------------------------------------------------
__global__ __launch_bounds__(256, 4) void k2_convproj(
    const float* __restrict__ xipre,
    const float* __restrict__ conv_w, const float* __restrict__ conv_b,
    const float* __restrict__ x_proj_w,
    const float* __restrict__ dt_proj_w, const float* __restrict__ dt_proj_b,
    const int* __restrict__ slot,
    float* __restrict__ xi_g, float* __restrict__ delta_g,
    float* __restrict__ bc_g)
{
  __shared__ float xibuf[64 * 129];   // 33 KB
  __shared__ float dtb[64 * 8];       // 2 KB: dt rows per token
  const int f = blockIdx.y;
  const int s = slot[f];
  if (s < 0) return;
  const int m0 = blockIdx.x * 64;
  const int tid = threadIdx.x;
  const int c = tid & 127;
  const int half = tid >> 7;
  const size_t rowbase = (size_t)s * T_TOK;
  const float4 cw = *(const float4*)(conv_w + c * 4);
  const float cb = conv_b[c];

  auto ldx = [&](int t) -> float {
    return (t >= 0) ? xipre[(rowbase + t) * C_CH + c] : 0.0f;   // t < T always here
  };

  // ---- conv + silu: 32 rows per thread-half; store to LDS + xi_g ----
  {
    const int t0 = m0 + half * 32;
    float xm1 = ldx(t0 - 1), xm2 = ldx(t0 - 2), xm3 = ldx(t0 - 3);
    #pragma unroll
    for (int i = 0; i < 32; ++i) {
      const float cur = ldx(t0 + i);
      const float sum = cw.x * xm3 + cw.y * xm2 + cw.z * xm1 + cw.w * cur + cb;
      const float xiv = fast_silu(sum);
      xibuf[(half * 32 + i) * 129 + c] = xiv;
      xi_g[(rowbase + t0 + i) * C_CH + c] = xiv;
      xm3 = xm2; xm2 = xm1; xm1 = cur;
    }
  }
  __syncthreads();
  // ---- projection 128->24: lane=token, wave handles 6 outputs ----
  {
    const int q6 = __builtin_amdgcn_readfirstlane(tid >> 6) * 6;  // wave's out base
    const int tok = tid & 63;
    float acc[6] = {0, 0, 0, 0, 0, 0};
    for (int cc = 0; cc < C_CH; ++cc) {
      const float xv = xibuf[tok * 129 + cc];
      #pragma unroll
      for (int jj = 0; jj < 6; ++jj)
        acc[jj] += xv * x_proj_w[cc * 24 + q6 + jj];   // scalar (uniform idx)
    }
    #pragma unroll
    for (int jj = 0; jj < 6; ++jj) {
      const int o = q6 + jj;                // wave-uniform
      if (o < 8) dtb[tok * 8 + o] = acc[jj];
      else       bc_g[(rowbase + m0 + tok) * 16 + (o - 8)] = acc[jj];
    }
  }
  __syncthreads();
  // ---- delta: lane=channel, 32 tokens per thread-half ----
  {
    float dw[8];
    #pragma unroll
    for (int r = 0; r < 8; ++r) dw[r] = dt_proj_w[r * C_CH + c];
    const float bias = dt_proj_b[c];
    for (int i = 0; i < 32; ++i) {
      const int tok = half * 32 + i;
      const float4 d0 = *(const float4*)&dtb[tok * 8];      // broadcast
      const float4 d1 = *(const float4*)&dtb[tok * 8 + 4];
      float pre = bias;
      pre += d0.x * dw[0] + d0.y * dw[1] + d0.z * dw[2] + d0.w * dw[3];
      pre += d1.x * dw[4] + d1.y * dw[5] + d1.z * dw[6] + d1.w * dw[7];
      const float dlt = fmaxf(pre, 0.0f) + __logf(1.0f + __expf(-fabsf(pre)));
      delta_g[(rowbase + m0 + tok) * C_CH + c] = dlt;
    }
  }
}

// ---------------------------------------------------------------------------
// K3_scan: pure bidirectional h-recurrence. Block = 256 threads = one
// 64-token chunk, waves 0-1 fwd / waves 2-3 bwd. Region [c0-32, c0+96),
// 96 steps per direction. Inputs xi/delta precomputed -> dA,u for a whole
// 8-step group are h-independent; critical path per step ~ 1 FMA.
// ---------------------------------------------------------------------------
__global__ __launch_bounds__(256, 4) void k3_scan(
    const float* __restrict__ xi_g, const float* __restrict__ delta_g,
    const float* __restrict__ wbuf, const float* __restrict__ bc_g,
    const float* __restrict__ A_log_f, const float* __restrict__ A_log_b,
    const float* __restrict__ D_f, const float* __restrict__ D_b,
    const int* __restrict__ slot, float* __restrict__ logit)
{
  __shared__ float bc[REGION * 16];       // 8.2 KB [region_row][0:8=B 8:16=C]
  const int f = blockIdx.y;
  const int s = slot[f];
  if (s < 0) return;
  const int c0 = blockIdx.x * CHUNK;
  const int r0 = c0 - RHALO;              // region start (may be negative)
  const int tid = threadIdx.x;
  const int c = tid & 127;                // channel
  const int half = tid >> 7;              // 0 = fwd waves, 1 = bwd waves
  const size_t rowbase = (size_t)s * T_TOK;

  // ---- stage B,C region slice: 128 rows x 16 floats = 512 float4 ----
  {
    const long grow = ((long)rowbase + r0) * 16;
    const int lo  = (r0 < 0) ? (-r0) * 4 : 0;
    const int hi  = (r0 + REGION > T_TOK) ? (T_TOK - r0) * 4 : REGION * 4;
    #pragma unroll
    for (int i = 0; i < 2; ++i) {
      const int idx = tid + i * 256;
      if (idx >= lo && idx < hi)
        *(float4*)&bc[idx * 4] = *(const float4*)&bc_g[grow + (long)idx * 4];
    }
  }
  __syncthreads();

  // ---- Scan setup ----
  float Ac[8];
  const float* Alog = half ? A_log_b : A_log_f;
  #pragma unroll
  for (int n = 0; n < NSTATE; ++n) Ac[n] = -expf(Alog[c * NSTATE + n]);
  const float Dd = half ? D_b[c] : D_f[c];
  float h[8] = {0, 0, 0, 0, 0, 0, 0, 0};

  // fast-decay eligibility: Ac[n] == (n+1)*Ac[0] (holds for this problem's A)
  const float a0 = Ac[0];
  int okl = 1;
  #pragma unroll
  for (int n = 1; n < NSTATE; ++n)
    okl &= (fabsf(Ac[n] - (float)(n + 1) * a0) <= 1e-4f * fabsf(Ac[n])) ? 1 : 0;
  const bool fastA = (__all(okl) != 0);   // wave-uniform

  auto decay8 = [&](float dlt, float* dA) {
    if (fastA) {
      const float e1 = __expf(dlt * a0);
      const float e2 = e1 * e1, e3 = e2 * e1, e4 = e2 * e2;
      dA[0] = e1; dA[1] = e2; dA[2] = e3; dA[3] = e4;
      dA[4] = e4 * e1; dA[5] = e4 * e2; dA[6] = e4 * e3; dA[7] = e4 * e4;
    } else {
      #pragma unroll
      for (int n = 0; n < NSTATE; ++n) dA[n] = __expf(dlt * Ac[n]);
    }
  };

  if (half == 0) {
    // forward: t from tb to c0+CHUNK-1
    const int tb = (r0 < 0) ? 0 : r0;
    const int outg0 = (c0 - tb) >> 3;        // first output group (4 or 0)
    const int ng = (c0 + CHUNK - tb) >> 3;   // 12 or 8
    for (int g = 0; g < ng; ++g) {
      const int t0 = tb + g * 8;
      const bool out = (g >= outg0);
      float xg[8], dg[8], wg[8];
      #pragma unroll
      for (int j = 0; j < 8; ++j) {
        const size_t gi = (rowbase + t0 + j) * C_CH + c;
        xg[j] = xi_g[gi];
        dg[j] = delta_g[gi];
        wg[j] = out ? wbuf[gi] : 0.0f;
      }
      #pragma unroll
      for (int j = 0; j < 8; ++j) {
        const int t = t0 + j;
        const int p = t - r0;
        const float dlt = dg[j];
        const float xiv = xg[j];
        const float u = dlt * xiv;
        const float4 b0 = *(const float4*)&bc[p * 16];
        const float4 b1 = *(const float4*)&bc[p * 16 + 4];
        float dA[8];
        decay8(dlt, dA);
        h[0] = dA[0] * h[0] + u * b0.x;
        h[1] = dA[1] * h[1] + u * b0.y;
        h[2] = dA[2] * h[2] + u * b0.z;
        h[3] = dA[3] * h[3] + u * b0.w;
        h[4] = dA[4] * h[4] + u * b1.x;
        h[5] = dA[5] * h[5] + u * b1.y;
        h[6] = dA[6] * h[6] + u * b1.z;
        h[7] = dA[7] * h[7] + u * b1.w;
        if (out) {
          const float4 cc0 = *(const float4*)&bc[p * 16 + 8];
          const float4 cc1 = *(const float4*)&bc[p * 16 + 12];
          float y = xiv * Dd;
          y += h[0] * cc0.x + h[1] * cc0.y + h[2] * cc0.z + h[3] * cc0.w;
          y += h[4] * cc1.x + h[5] * cc1.y + h[6] * cc1.z + h[7] * cc1.w;
          float contrib = y * wg[j];
          contrib += __shfl_xor(contrib, 1);
          contrib += __shfl_xor(contrib, 2);
          contrib += __shfl_xor(contrib, 4);
          contrib += __shfl_xor(contrib, 8);
          contrib += __shfl_xor(contrib, 16);
          contrib += __shfl_xor(contrib, 32);
          if ((tid & 63) == 0) atomicAdd(&logit[rowbase + t], contrib);
        }
      }
    }
  } else {
    // backward: t from te2-1 down to c0
    const int te2e = r0 + REGION;
    const int te2 = (te2e > T_TOK) ? T_TOK : te2e;
    const int outg0 = (te2 - (c0 + CHUNK)) >> 3;  // 4 or 0
    const int ng = (te2 - c0) >> 3;               // 12 or 8
    for (int g = 0; g < ng; ++g) {
      const int t0 = te2 - 1 - g * 8;
      const bool out = (g >= outg0);
      float xg[8], dg[8], wg[8];
      #pragma unroll
      for (int j = 0; j < 8; ++j) {
        const size_t gi = (rowbase + t0 - j) * C_CH + c;
        xg[j] = xi_g[gi];
        dg[j] = delta_g[gi];
        wg[j] = out ? wbuf[gi] : 0.0f;
      }
      #pragma unroll
      for (int j = 0; j < 8; ++j) {
        const int t = t0 - j;
        const int p = t - r0;
        const float dlt = dg[j];
        const float xiv = xg[j];
        const float u = dlt * xiv;
        const float4 b0 = *(const float4*)&bc[p * 16];
        const float4 b1 = *(const float4*)&bc[p * 16 + 4];
        float dA[8];
        decay8(dlt, dA);
        h[0] = dA[0] * h[0] + u * b0.x;
        h[1] = dA[1] * h[1] + u * b0.y;
        h[2] = dA[2] * h[2] + u * b0.z;
        h[3] = dA[3] * h[3] + u * b0.w;
        h[4] = dA[4] * h[4] + u * b1.x;
        h[5] = dA[5] * h[5] + u * b1.y;
        h[6] = dA[6] * h[6] + u * b1.z;
        h[7] = dA[7] * h[7] + u * b1.w;
        if (out) {
          const float4 cc0 = *(const float4*)&bc[p * 16 + 8];
          const float4 cc1 = *(const float4*)&bc[p * 16 + 12];
          float y = xiv * Dd;
          y += h[0] * cc0.x + h[1] * cc0.y + h[2] * cc0.z + h[3] * cc0.w;
          y += h[4] * cc1.x + h[5] * cc1.y + h[6] * cc1.z + h[7] * cc1.w;
          float contrib = y * wg[j];
          contrib += __shfl_xor(contrib, 1);
          contrib += __shfl_xor(contrib, 2);
          contrib += __shfl_xor(contrib, 4);
          contrib += __shfl_xor(contrib, 8);
          contrib += __shfl_xor(contrib, 16);
          contrib += __shfl_xor(contrib, 32);
          if ((tid & 63) == 0) atomicAdd(&logit[rowbase + t], contrib);
        }
      }
    }
  }
}

// ---------------------------------------------------------------------------
// K4: threshold (sigmoid(lg)>0.5 <=> lg>0, exact) + 3x3 max pool. ego -> 1.
// ---------------------------------------------------------------------------
__global__ __launch_bounds__(128) void k4_pool(
    const float* __restrict__ logit, const int* __restrict__ slot,
    float* __restrict__ out)
{
  const int w = threadIdx.x;
  if (w >= W_IMG) return;
  const int hh = blockIdx.x;
  const int f = blockIdx.y;
  const int s = slot[f];
  float m = 0.0f;
  if (s < 0) {
    m = 1.0f;
  } else {
    for (int dh = -1; dh <= 1; ++dh) {
      const int h2 = hh + dh;
      if (h2 < 0 || h2 >= H_IMG) continue;
      for (int dw = -1; dw <= 1; ++dw) {
        const int w2 = w + dw;
        if (w2 < 0 || w2 >= W_IMG) continue;
        if (logit[(size_t)s * T_TOK + h2 * W_IMG + w2] > 0.0f) m = 1.0f;
      }
    }
  }
  out[(size_t)f * T_TOK + hh * W_IMG + w] = m;
}

// ---------------------------------------------------------------------------
extern "C" void kernel_launch(void* const* d_in, const int* in_sizes, int n_in,
                              void* d_out, int out_size, void* d_ws, size_t ws_size,
                              hipStream_t stream) {
  const float* feats      = (const float*)d_in[0];
  const float* in_proj    = (const float*)d_in[1];
  const float* conv_w     = (const float*)d_in[2];
  const float* conv_b     = (const float*)d_in[3];
  const float* x_proj_w   = (const float*)d_in[4];
  const float* dt_proj_w  = (const float*)d_in[5];
  const float* dt_proj_b  = (const float*)d_in[6];
  const float* A_log_f    = (const float*)d_in[7];
  const float* A_log_b    = (const float*)d_in[8];
  const float* D_f        = (const float*)d_in[9];
  const float* D_b        = (const float*)d_in[10];
  const float* out_proj_w = (const float*)d_in[11];
  const float* rms_w      = (const float*)d_in[12];
  const float* mlp_w      = (const float*)d_in[13];
  const float* mlp_b      = (const float*)d_in[14];
  const int*   rec        = (const int*)d_in[15];   // int32! (jax downcasts int64)

  const int N = in_sizes[0] / (C_CH * T_TOK);
  const int n_groups = in_sizes[15];
  int S = N - n_groups;
  if (S < 1) S = 1;

  // workspace carve-up (~137 MB at S=7)
  char* p = (char*)d_ws;
  float* vvec  = (float*)p; p += 1024;
  int*   slot  = (int*)p;   p += ((N * 4 + 255) / 256) * 256;
  float* logit = (float*)p; p += (size_t)S * T_TOK * 4;
  float* xipre = (float*)p; p += (size_t)S * T_TOK * C_CH * 4;
  float* wA    = (float*)p; p += (size_t)S * T_TOK * C_CH * 4;
  float* xig   = (float*)p; p += (size_t)S * T_TOK * C_CH * 4;
  float* dltg  = (float*)p; p += (size_t)S * T_TOK * C_CH * 4;
  float* bcg   = (float*)p; p += (size_t)S * T_TOK * 16 * 4;
  (void)ws_size; (void)n_in; (void)out_size;

  k0_setup<<<1, 128, 0, stream>>>(rec, n_groups, N, out_proj_w, mlp_w, vvec, slot);
  k1_gemm<<<dim3(T_TOK / 32, N), 256, 0, stream>>>(
      feats, in_proj, rms_w, mlp_w, mlp_b, vvec, slot, xipre, wA, logit);
  k2_convproj<<<dim3(T_TOK / 64, N), 256, 0, stream>>>(
      xipre, conv_w, conv_b, x_proj_w, dt_proj_w, dt_proj_b, slot,
      xig, dltg, bcg);
  k3_scan<<<dim3(T_TOK / CHUNK, N), 256, 0, stream>>>(
      xig, dltg, wA, bcg, A_log_f, A_log_b, D_f, D_b, slot, logit);
  k4_pool<<<dim3(H_IMG, N), 128, 0, stream>>>(logit, slot, (float*)d_out);
}

// Round 8
// 316.397 us; speedup vs baseline: 1.1215x; 1.1215x over previous
//
#include <hip/hip_runtime.h>
#include <cstdint>
#include <cstddef>

#define C_CH 128
#define T_TOK 9216
#define H_IMG 96
#define W_IMG 96
#define NSTATE 8

// fused scan tiling: 64 output tokens, 32-token warm-up halo each direction.
#define CHUNK 64
#define RHALO 32
#define REGION (CHUNK + 2 * RHALO)   // 128

__device__ __forceinline__ float siluf_dev(float x) {
  return x / (1.0f + expf(-x));
}

__device__ __forceinline__ float fast_silu(float x) {
  // x * sigmoid(x) with native rcp; binary-thresholded output tolerates ~2ulp
  return __fdividef(x, 1.0f + __expf(-x));
}

// ---------------------------------------------------------------------------
// K0: slot assignment from record_len (int32!) + v = out_proj_w @ mlp_w
// ---------------------------------------------------------------------------
__global__ __launch_bounds__(128) void k0_setup(
    const int* __restrict__ rec, int n_groups, int N,
    const float* __restrict__ out_proj_w, const float* __restrict__ mlp_w,
    float* __restrict__ vvec, int* __restrict__ slot)
{
  const int tid = threadIdx.x;
  if (tid == 0) {
    int f = 0, sl = 0;
    for (int g = 0; g < n_groups; ++g) {
      const int L = rec[g];
      slot[f] = -1;                       // ego / single frame -> mask = 1
      for (int i = 1; i < L; ++i) slot[f + i] = sl++;
      f += L;
    }
  }
  if (tid < C_CH) {
    float acc = 0.0f;
    for (int j = 0; j < C_CH; ++j) acc += out_proj_w[tid * C_CH + j] * mlp_w[j];
    vvec[tid] = acc;
  }
}

// ---------------------------------------------------------------------------
// K1: rmsnorm + xz = xn @ in_proj  (M=64 token tile, K=128, N=256).
// R8: single k-loop computing ALL 4 N-chunks -> acc[4][16] (64 VGPR).
// Per k: 1 ds_read_b128 (a4) + 4 independent global b4 streams + 64 FMA
// (~140 cy issue to hide the loads; R7's failure was VGPR=32 -> no ILP).
// launch_bounds(256,4) -> 128-VGPR budget; LDS 35.3 KB -> 4 blocks/CU;
// all 1008 blocks co-resident. FMA order per output unchanged (k ascending)
// -> bit-identical to R6.
// ---------------------------------------------------------------------------
__global__ __launch_bounds__(256, 4) void k1_gemm(
    const float* __restrict__ feats, const float* __restrict__ in_proj,
    const float* __restrict__ rms_w, const float* __restrict__ mlp_w,
    const float* __restrict__ mlp_b, const float* __restrict__ vvec,
    const int* __restrict__ slot,
    float* __restrict__ xipre, float* __restrict__ wbuf,
    float* __restrict__ logit)
{
  __shared__ float Asm[C_CH * 64];   // A[k][t]  (raw x, then ir*rw-scaled) 32 KB
  __shared__ float redA[256], redB[256], irS[64];
  const int f = blockIdx.y;
  const int s = slot[f];
  if (s < 0) return;
  const int m0 = blockIdx.x * 64;
  const int tid = threadIdx.x;

  // stage A: x[c][t], coalesced along t
  {
    const int c0 = tid >> 4;
    const int tq = (tid & 15) * 4;
    const float* src = feats + (size_t)f * C_CH * T_TOK + m0 + tq;
    #pragma unroll
    for (int i = 0; i < 8; ++i) {
      const int c = c0 + i * 16;
      const float4 x4 = *(const float4*)(src + (size_t)c * T_TOK);
      *(float4*)&Asm[c * 64 + tq] = x4;
    }
  }
  __syncthreads();
  // pre-pass: per-token rms + logit init (res . mlp_w + b), 4 threads/token
  {
    const int t = tid & 63;
    const int q = tid >> 6;
    float ssum = 0.0f, rm = 0.0f;
    for (int cc = q * 32; cc < q * 32 + 32; ++cc) {
      const float val = Asm[cc * 64 + t];
      ssum += val * val;
      rm += val * mlp_w[cc];
    }
    redA[tid] = ssum; redB[tid] = rm;
  }
  __syncthreads();
  if (tid < 64) {
    const int t = tid;
    const float ssum = redA[t] + redA[t + 64] + redA[t + 128] + redA[t + 192];
    const float rm   = redB[t] + redB[t + 64] + redB[t + 128] + redB[t + 192];
    const float ir = 1.0f / sqrtf(ssum * (1.0f / C_CH) + 1e-5f);
    logit[(size_t)s * T_TOK + m0 + t] = rm + mlp_b[0];
    irS[t] = ir;
  }
  __syncthreads();
  {
    const int t = tid & 63;
    const int q = tid >> 6;
    const float ir = irS[t];
    for (int cc = q * 32; cc < q * 32 + 32; ++cc)
      Asm[cc * 64 + t] = (Asm[cc * 64 + t] * ir) * rms_w[cc];
  }
  __syncthreads();

  const int ti = tid >> 4;   // 0..15 -> rows ti*4..+3
  const int tc = tid & 15;   // 0..15 -> cols tc*4..+3 (within each 64-chunk)
  float acc[4][16];
  #pragma unroll
  for (int i = 0; i < 4; ++i)
    #pragma unroll
    for (int j = 0; j < 16; ++j) acc[i][j] = 0.0f;

  {
    const float* bp = in_proj + tc * 4;
    #pragma unroll 2
    for (int k = 0; k < C_CH; ++k) {
      const float4 b0 = *(const float4*)(bp + (size_t)k * 256);
      const float4 b1 = *(const float4*)(bp + (size_t)k * 256 + 64);
      const float4 b2 = *(const float4*)(bp + (size_t)k * 256 + 128);
      const float4 b3 = *(const float4*)(bp + (size_t)k * 256 + 192);
      const float4 a4 = *(const float4*)&Asm[k * 64 + ti * 4];
      #pragma unroll
      for (int i = 0; i < 4; ++i) {
        const float av = (i == 0) ? a4.x : (i == 1) ? a4.y : (i == 2) ? a4.z : a4.w;
        acc[i][0]  += av * b0.x; acc[i][1]  += av * b0.y; acc[i][2]  += av * b0.z; acc[i][3]  += av * b0.w;
        acc[i][4]  += av * b1.x; acc[i][5]  += av * b1.y; acc[i][6]  += av * b1.z; acc[i][7]  += av * b1.w;
        acc[i][8]  += av * b2.x; acc[i][9]  += av * b2.y; acc[i][10] += av * b2.z; acc[i][11] += av * b2.w;
        acc[i][12] += av * b3.x; acc[i][13] += av * b3.y; acc[i][14] += av * b3.z; acc[i][15] += av * b3.w;
      }
    }
  }

  // epilogue: chunks 0,1 -> xipre (xi channels); chunks 2,3 -> wbuf (z channels)
  {
    const float4 v4a = *(const float4*)&vvec[tc * 4];        // z chunk 2
    const float4 v4b = *(const float4*)&vvec[64 + tc * 4];   // z chunk 3
    #pragma unroll
    for (int i = 0; i < 4; ++i) {
      const int t = m0 + ti * 4 + i;
      float* xrow = &xipre[((size_t)s * T_TOK + t) * C_CH];
      float* wrow = &wbuf[((size_t)s * T_TOK + t) * C_CH];
      float4 o0; o0.x = acc[i][0]; o0.y = acc[i][1]; o0.z = acc[i][2]; o0.w = acc[i][3];
      float4 o1; o1.x = acc[i][4]; o1.y = acc[i][5]; o1.z = acc[i][6]; o1.w = acc[i][7];
      *(float4*)&xrow[tc * 4] = o0;
      *(float4*)&xrow[64 + tc * 4] = o1;
      float4 w0, w1;
      w0.x = 0.5f * siluf_dev(acc[i][8])  * v4a.x;
      w0.y = 0.5f * siluf_dev(acc[i][9])  * v4a.y;
      w0.z = 0.5f * siluf_dev(acc[i][10]) * v4a.z;
      w0.w = 0.5f * siluf_dev(acc[i][11]) * v4a.w;
      w1.x = 0.5f * siluf_dev(acc[i][12]) * v4b.x;
      w1.y = 0.5f * siluf_dev(acc[i][13]) * v4b.y;
      w1.z = 0.5f * siluf_dev(acc[i][14]) * v4b.z;
      w1.w = 0.5f * siluf_dev(acc[i][15]) * v4b.w;
      *(float4*)&wrow[tc * 4] = w0;
      *(float4*)&wrow[64 + tc * 4] = w1;
    }
  }
}

// ---------------------------------------------------------------------------
// K2: conv+silu -> xi_g[t][c]; projection -> B,C -> bc_g[t][16] and dt -> LDS;
// delta[t][c] = softplus(dt . dt_proj_w[:,c] + b[c]) -> delta_g[t][c].
// LDS: xibuf 33 KB + dtb 2 KB = 35 KB, 4 blocks/CU.
// ---------------------------------------------------------------------------
__global__ __launch_bounds__(256, 4) void k2_convproj(
    const float* __restrict__ xipre,
    const float* __restrict__ conv_w, const float* __restrict__ conv_b,
    const float* __restrict__ x_proj_w,
    const float* __restrict__ dt_proj_w, const float* __restrict__ dt_proj_b,
    const int* __restrict__ slot,
    float* __restrict__ xi_g, float* __restrict__ delta_g,
    float* __restrict__ bc_g)
{
  __shared__ float xibuf[64 * 129];   // 33 KB
  __shared__ float dtb[64 * 8];       // 2 KB: dt rows per token
  const int f = blockIdx.y;
  const int s = slot[f];
  if (s < 0) return;
  const int m0 = blockIdx.x * 64;
  const int tid = threadIdx.x;
  const int c = tid & 127;
  const int half = tid >> 7;
  const size_t rowbase = (size_t)s * T_TOK;
  const float4 cw = *(const float4*)(conv_w + c * 4);
  const float cb = conv_b[c];

  auto ldx = [&](int t) -> float {
    return (t >= 0) ? xipre[(rowbase + t) * C_CH + c] : 0.0f;   // t < T always here
  };

  // ---- conv + silu: 32 rows per thread-half; store to LDS + xi_g ----
  {
    const int t0 = m0 + half * 32;
    float xm1 = ldx(t0 - 1), xm2 = ldx(t0 - 2), xm3 = ldx(t0 - 3);
    #pragma unroll
    for (int i = 0; i < 32; ++i) {
      const float cur = ldx(t0 + i);
      const float sum = cw.x * xm3 + cw.y * xm2 + cw.z * xm1 + cw.w * cur + cb;
      const float xiv = fast_silu(sum);
      xibuf[(half * 32 + i) * 129 + c] = xiv;
      xi_g[(rowbase + t0 + i) * C_CH + c] = xiv;
      xm3 = xm2; xm2 = xm1; xm1 = cur;
    }
  }
  __syncthreads();
  // ---- projection 128->24: lane=token, wave handles 6 outputs ----
  {
    const int q6 = __builtin_amdgcn_readfirstlane(tid >> 6) * 6;  // wave's out base
    const int tok = tid & 63;
    float acc[6] = {0, 0, 0, 0, 0, 0};
    for (int cc = 0; cc < C_CH; ++cc) {
      const float xv = xibuf[tok * 129 + cc];
      #pragma unroll
      for (int jj = 0; jj < 6; ++jj)
        acc[jj] += xv * x_proj_w[cc * 24 + q6 + jj];   // scalar (uniform idx)
    }
    #pragma unroll
    for (int jj = 0; jj < 6; ++jj) {
      const int o = q6 + jj;                // wave-uniform
      if (o < 8) dtb[tok * 8 + o] = acc[jj];
      else       bc_g[(rowbase + m0 + tok) * 16 + (o - 8)] = acc[jj];
    }
  }
  __syncthreads();
  // ---- delta: lane=channel, 32 tokens per thread-half ----
  {
    float dw[8];
    #pragma unroll
    for (int r = 0; r < 8; ++r) dw[r] = dt_proj_w[r * C_CH + c];
    const float bias = dt_proj_b[c];
    for (int i = 0; i < 32; ++i) {
      const int tok = half * 32 + i;
      const float4 d0 = *(const float4*)&dtb[tok * 8];      // broadcast
      const float4 d1 = *(const float4*)&dtb[tok * 8 + 4];
      float pre = bias;
      pre += d0.x * dw[0] + d0.y * dw[1] + d0.z * dw[2] + d0.w * dw[3];
      pre += d1.x * dw[4] + d1.y * dw[5] + d1.z * dw[6] + d1.w * dw[7];
      const float dlt = fmaxf(pre, 0.0f) + __logf(1.0f + __expf(-fabsf(pre)));
      delta_g[(rowbase + m0 + tok) * C_CH + c] = dlt;
    }
  }
}

// ---------------------------------------------------------------------------
// K3_scan: pure bidirectional h-recurrence. Block = 256 threads = one
// 64-token chunk, waves 0-1 fwd / waves 2-3 bwd. Region [c0-32, c0+96),
// 96 steps per direction. Inputs xi/delta precomputed -> dA,u for a whole
// 8-step group are h-independent; critical path per step ~ 1 FMA.
// ---------------------------------------------------------------------------
__global__ __launch_bounds__(256, 4) void k3_scan(
    const float* __restrict__ xi_g, const float* __restrict__ delta_g,
    const float* __restrict__ wbuf, const float* __restrict__ bc_g,
    const float* __restrict__ A_log_f, const float* __restrict__ A_log_b,
    const float* __restrict__ D_f, const float* __restrict__ D_b,
    const int* __restrict__ slot, float* __restrict__ logit)
{
  __shared__ float bc[REGION * 16];       // 8.2 KB [region_row][0:8=B 8:16=C]
  const int f = blockIdx.y;
  const int s = slot[f];
  if (s < 0) return;
  const int c0 = blockIdx.x * CHUNK;
  const int r0 = c0 - RHALO;              // region start (may be negative)
  const int tid = threadIdx.x;
  const int c = tid & 127;                // channel
  const int half = tid >> 7;              // 0 = fwd waves, 1 = bwd waves
  const size_t rowbase = (size_t)s * T_TOK;

  // ---- stage B,C region slice: 128 rows x 16 floats = 512 float4 ----
  {
    const long grow = ((long)rowbase + r0) * 16;
    const int lo  = (r0 < 0) ? (-r0) * 4 : 0;
    const int hi  = (r0 + REGION > T_TOK) ? (T_TOK - r0) * 4 : REGION * 4;
    #pragma unroll
    for (int i = 0; i < 2; ++i) {
      const int idx = tid + i * 256;
      if (idx >= lo && idx < hi)
        *(float4*)&bc[idx * 4] = *(const float4*)&bc_g[grow + (long)idx * 4];
    }
  }
  __syncthreads();

  // ---- Scan setup ----
  float Ac[8];
  const float* Alog = half ? A_log_b : A_log_f;
  #pragma unroll
  for (int n = 0; n < NSTATE; ++n) Ac[n] = -expf(Alog[c * NSTATE + n]);
  const float Dd = half ? D_b[c] : D_f[c];
  float h[8] = {0, 0, 0, 0, 0, 0, 0, 0};

  // fast-decay eligibility: Ac[n] == (n+1)*Ac[0] (holds for this problem's A)
  const float a0 = Ac[0];
  int okl = 1;
  #pragma unroll
  for (int n = 1; n < NSTATE; ++n)
    okl &= (fabsf(Ac[n] - (float)(n + 1) * a0) <= 1e-4f * fabsf(Ac[n])) ? 1 : 0;
  const bool fastA = (__all(okl) != 0);   // wave-uniform

  auto decay8 = [&](float dlt, float* dA) {
    if (fastA) {
      const float e1 = __expf(dlt * a0);
      const float e2 = e1 * e1, e3 = e2 * e1, e4 = e2 * e2;
      dA[0] = e1; dA[1] = e2; dA[2] = e3; dA[3] = e4;
      dA[4] = e4 * e1; dA[5] = e4 * e2; dA[6] = e4 * e3; dA[7] = e4 * e4;
    } else {
      #pragma unroll
      for (int n = 0; n < NSTATE; ++n) dA[n] = __expf(dlt * Ac[n]);
    }
  };

  if (half == 0) {
    // forward: t from tb to c0+CHUNK-1
    const int tb = (r0 < 0) ? 0 : r0;
    const int outg0 = (c0 - tb) >> 3;        // first output group (4 or 0)
    const int ng = (c0 + CHUNK - tb) >> 3;   // 12 or 8
    for (int g = 0; g < ng; ++g) {
      const int t0 = tb + g * 8;
      const bool out = (g >= outg0);
      float xg[8], dg[8], wg[8];
      #pragma unroll
      for (int j = 0; j < 8; ++j) {
        const size_t gi = (rowbase + t0 + j) * C_CH + c;
        xg[j] = xi_g[gi];
        dg[j] = delta_g[gi];
        wg[j] = out ? wbuf[gi] : 0.0f;
      }
      #pragma unroll
      for (int j = 0; j < 8; ++j) {
        const int t = t0 + j;
        const int p = t - r0;
        const float dlt = dg[j];
        const float xiv = xg[j];
        const float u = dlt * xiv;
        const float4 b0 = *(const float4*)&bc[p * 16];
        const float4 b1 = *(const float4*)&bc[p * 16 + 4];
        float dA[8];
        decay8(dlt, dA);
        h[0] = dA[0] * h[0] + u * b0.x;
        h[1] = dA[1] * h[1] + u * b0.y;
        h[2] = dA[2] * h[2] + u * b0.z;
        h[3] = dA[3] * h[3] + u * b0.w;
        h[4] = dA[4] * h[4] + u * b1.x;
        h[5] = dA[5] * h[5] + u * b1.y;
        h[6] = dA[6] * h[6] + u * b1.z;
        h[7] = dA[7] * h[7] + u * b1.w;
        if (out) {
          const float4 cc0 = *(const float4*)&bc[p * 16 + 8];
          const float4 cc1 = *(const float4*)&bc[p * 16 + 12];
          float y = xiv * Dd;
          y += h[0] * cc0.x + h[1] * cc0.y + h[2] * cc0.z + h[3] * cc0.w;
          y += h[4] * cc1.x + h[5] * cc1.y + h[6] * cc1.z + h[7] * cc1.w;
          float contrib = y * wg[j];
          contrib += __shfl_xor(contrib, 1);
          contrib += __shfl_xor(contrib, 2);
          contrib += __shfl_xor(contrib, 4);
          contrib += __shfl_xor(contrib, 8);
          contrib += __shfl_xor(contrib, 16);
          contrib += __shfl_xor(contrib, 32);
          if ((tid & 63) == 0) atomicAdd(&logit[rowbase + t], contrib);
        }
      }
    }
  } else {
    // backward: t from te2-1 down to c0
    const int te2e = r0 + REGION;
    const int te2 = (te2e > T_TOK) ? T_TOK : te2e;
    const int outg0 = (te2 - (c0 + CHUNK)) >> 3;  // 4 or 0
    const int ng = (te2 - c0) >> 3;               // 12 or 8
    for (int g = 0; g < ng; ++g) {
      const int t0 = te2 - 1 - g * 8;
      const bool out = (g >= outg0);
      float xg[8], dg[8], wg[8];
      #pragma unroll
      for (int j = 0; j < 8; ++j) {
        const size_t gi = (rowbase + t0 - j) * C_CH + c;
        xg[j] = xi_g[gi];
        dg[j] = delta_g[gi];
        wg[j] = out ? wbuf[gi] : 0.0f;
      }
      #pragma unroll
      for (int j = 0; j < 8; ++j) {
        const int t = t0 - j;
        const int p = t - r0;
        const float dlt = dg[j];
        const float xiv = xg[j];
        const float u = dlt * xiv;
        const float4 b0 = *(const float4*)&bc[p * 16];
        const float4 b1 = *(const float4*)&bc[p * 16 + 4];
        float dA[8];
        decay8(dlt, dA);
        h[0] = dA[0] * h[0] + u * b0.x;
        h[1] = dA[1] * h[1] + u * b0.y;
        h[2] = dA[2] * h[2] + u * b0.z;
        h[3] = dA[3] * h[3] + u * b0.w;
        h[4] = dA[4] * h[4] + u * b1.x;
        h[5] = dA[5] * h[5] + u * b1.y;
        h[6] = dA[6] * h[6] + u * b1.z;
        h[7] = dA[7] * h[7] + u * b1.w;
        if (out) {
          const float4 cc0 = *(const float4*)&bc[p * 16 + 8];
          const float4 cc1 = *(const float4*)&bc[p * 16 + 12];
          float y = xiv * Dd;
          y += h[0] * cc0.x + h[1] * cc0.y + h[2] * cc0.z + h[3] * cc0.w;
          y += h[4] * cc1.x + h[5] * cc1.y + h[6] * cc1.z + h[7] * cc1.w;
          float contrib = y * wg[j];
          contrib += __shfl_xor(contrib, 1);
          contrib += __shfl_xor(contrib, 2);
          contrib += __shfl_xor(contrib, 4);
          contrib += __shfl_xor(contrib, 8);
          contrib += __shfl_xor(contrib, 16);
          contrib += __shfl_xor(contrib, 32);
          if ((tid & 63) == 0) atomicAdd(&logit[rowbase + t], contrib);
        }
      }
    }
  }
}

// ---------------------------------------------------------------------------
// K4: threshold (sigmoid(lg)>0.5 <=> lg>0, exact) + 3x3 max pool. ego -> 1.
// ---------------------------------------------------------------------------
__global__ __launch_bounds__(128) void k4_pool(
    const float* __restrict__ logit, const int* __restrict__ slot,
    float* __restrict__ out)
{
  const int w = threadIdx.x;
  if (w >= W_IMG) return;
  const int hh = blockIdx.x;
  const int f = blockIdx.y;
  const int s = slot[f];
  float m = 0.0f;
  if (s < 0) {
    m = 1.0f;
  } else {
    for (int dh = -1; dh <= 1; ++dh) {
      const int h2 = hh + dh;
      if (h2 < 0 || h2 >= H_IMG) continue;
      for (int dw = -1; dw <= 1; ++dw) {
        const int w2 = w + dw;
        if (w2 < 0 || w2 >= W_IMG) continue;
        if (logit[(size_t)s * T_TOK + h2 * W_IMG + w2] > 0.0f) m = 1.0f;
      }
    }
  }
  out[(size_t)f * T_TOK + hh * W_IMG + w] = m;
}

// ---------------------------------------------------------------------------
extern "C" void kernel_launch(void* const* d_in, const int* in_sizes, int n_in,
                              void* d_out, int out_size, void* d_ws, size_t ws_size,
                              hipStream_t stream) {
  const float* feats      = (const float*)d_in[0];
  const float* in_proj    = (const float*)d_in[1];
  const float* conv_w     = (const float*)d_in[2];
  const float* conv_b     = (const float*)d_in[3];
  const float* x_proj_w   = (const float*)d_in[4];
  const float* dt_proj_w  = (const float*)d_in[5];
  const float* dt_proj_b  = (const float*)d_in[6];
  const float* A_log_f    = (const float*)d_in[7];
  const float* A_log_b    = (const float*)d_in[8];
  const float* D_f        = (const float*)d_in[9];
  const float* D_b        = (const float*)d_in[10];
  const float* out_proj_w = (const float*)d_in[11];
  const float* rms_w      = (const float*)d_in[12];
  const float* mlp_w      = (const float*)d_in[13];
  const float* mlp_b      = (const float*)d_in[14];
  const int*   rec        = (const int*)d_in[15];   // int32! (jax downcasts int64)

  const int N = in_sizes[0] / (C_CH * T_TOK);
  const int n_groups = in_sizes[15];
  int S = N - n_groups;
  if (S < 1) S = 1;

  // workspace carve-up (~137 MB at S=7)
  char* p = (char*)d_ws;
  float* vvec  = (float*)p; p += 1024;
  int*   slot  = (int*)p;   p += ((N * 4 + 255) / 256) * 256;
  float* logit = (float*)p; p += (size_t)S * T_TOK * 4;
  float* xipre = (float*)p; p += (size_t)S * T_TOK * C_CH * 4;
  float* wA    = (float*)p; p += (size_t)S * T_TOK * C_CH * 4;
  float* xig   = (float*)p; p += (size_t)S * T_TOK * C_CH * 4;
  float* dltg  = (float*)p; p += (size_t)S * T_TOK * C_CH * 4;
  float* bcg   = (float*)p; p += (size_t)S * T_TOK * 16 * 4;
  (void)ws_size; (void)n_in; (void)out_size;

  k0_setup<<<1, 128, 0, stream>>>(rec, n_groups, N, out_proj_w, mlp_w, vvec, slot);
  k1_gemm<<<dim3(T_TOK / 64, N), 256, 0, stream>>>(
      feats, in_proj, rms_w, mlp_w, mlp_b, vvec, slot, xipre, wA, logit);
  k2_convproj<<<dim3(T_TOK / 64, N), 256, 0, stream>>>(
      xipre, conv_w, conv_b, x_proj_w, dt_proj_w, dt_proj_b, slot,
      xig, dltg, bcg);
  k3_scan<<<dim3(T_TOK / CHUNK, N), 256, 0, stream>>>(
      xig, dltg, wA, bcg, A_log_f, A_log_b, D_f, D_b, slot, logit);
  k4_pool<<<dim3(H_IMG, N), 128, 0, stream>>>(logit, slot, (float*)d_out);
}